// Round 11
// baseline (1014.738 us; speedup 1.0000x reference)
//
#include <hip/hip_runtime.h>
#include <hip/hip_bf16.h>
#include <hip/hip_fp16.h>
#include <cmath>

typedef __attribute__((ext_vector_type(8))) short short8_t;
typedef __attribute__((ext_vector_type(4))) float f32x4;

static __device__ __forceinline__ short f2bs(float f) {
    union { __hip_bfloat16 h; short s; } u;
    u.h = __float2bfloat16(f);
    return u.s;
}
static __device__ __forceinline__ float bs2f(unsigned int us) {
    union { float f; unsigned int i; } u;
    u.i = us << 16;
    return u.f;
}
static __device__ __forceinline__ unsigned int pack2bf(float a, float b) {
    return (unsigned int)(unsigned short)f2bs(a) |
           ((unsigned int)(unsigned short)f2bs(b) << 16);
}
// Barrier that waits only on LDS ops (lgkmcnt), NOT vmem.
static __device__ __forceinline__ void lds_barrier() {
    asm volatile("s_waitcnt lgkmcnt(0)\n\ts_barrier" ::: "memory");
}

// ---------------------------------------------------------------------------
// Pack kernel: Wd/W1/W2 -> bf16 MFMA B-fragment order; M = W0t @ We (fp32).
// ---------------------------------------------------------------------------
__global__ void pack_kernel(const float* __restrict__ Wd,
                            const float* __restrict__ W1,
                            const float* __restrict__ W2,
                            const float* __restrict__ W0,
                            const float* __restrict__ We,
                            short* __restrict__ pWd,
                            short* __restrict__ pW1,
                            short* __restrict__ pW2,
                            float* __restrict__ Mb)
{
    const int tid = blockIdx.x * blockDim.x + threadIdx.x;
    const int stride = gridDim.x * blockDim.x;
    for (int i = tid; i < 6 * 32768; i += stride) {
        int c = i >> 15, rem = i & 32767;
        int f = rem >> 9, l = (rem >> 3) & 63, j = rem & 7;
        int kk = f >> 4, nt = f & 15;
        int k = kk * 32 + (l >> 4) * 8 + j;
        int n = nt * 16 + (l & 15);
        pWd[i] = f2bs(Wd[(size_t)c * 32768 + k * 256 + n]);
    }
    for (int i = tid; i < 6 * 16384; i += stride) {
        int c = i >> 14, rem = i & 16383;
        int f = rem >> 9, l = (rem >> 3) & 63, j = rem & 7;
        int kk = f >> 3, nt = f & 7;
        int k = kk * 32 + (l >> 4) * 8 + j;
        int n = nt * 16 + (l & 15);
        pW1[i] = f2bs(W1[(size_t)c * 16384 + k * 128 + n]);
        pW2[i] = f2bs(W2[(size_t)c * 16384 + k * 128 + n]);
    }
    for (int i = tid; i < 6 * 512; i += stride) {
        int c = i >> 9, rem = i & 511;
        int a = rem >> 7, h = rem & 127;
        int t = c % 3;
        float m = 0.f;
        #pragma unroll
        for (int j = 0; j < 4; ++j)
            m = fmaf(W0[t * 16 + a * 4 + j], We[(size_t)c * 512 + j * 128 + h], m);
        Mb[i] = m;
    }
}

// ---------------------------------------------------------------------------
// Convert fp32 -> bf16 (two arrays)
// ---------------------------------------------------------------------------
__global__ void tobf16_kernel(const float* __restrict__ a, const float* __restrict__ b,
                              unsigned short* __restrict__ oa, unsigned short* __restrict__ ob,
                              int n4)
{
    int i = blockIdx.x * blockDim.x + threadIdx.x;
    const int stride = gridDim.x * blockDim.x;
    for (; i < n4; i += stride) {
        float4 va = ((const float4*)a)[i];
        uint2 pa; pa.x = pack2bf(va.x, va.y); pa.y = pack2bf(va.z, va.w);
        ((uint2*)oa)[i] = pa;
        float4 vb = ((const float4*)b)[i];
        uint2 pb; pb.x = pack2bf(vb.x, vb.y); pb.y = pack2bf(vb.z, vb.w);
        ((uint2*)ob)[i] = pb;
    }
}

// ---------------------------------------------------------------------------
// Counting-sort kernels. Sorted edges are packed into ONE 32B record:
//   rec[p] = { ew, src(asfloat), dst(asfloat), pad | ea.x, ea.y, ea.z, ea.w }
// (R10 lesson: scattering 4 separate arrays = 4 random 64B-line RMWs/edge.)
// ---------------------------------------------------------------------------
__global__ void hist_kernel(const int* __restrict__ ei, int* __restrict__ cnt, int E)
{
    for (int e = blockIdx.x * blockDim.x + threadIdx.x; e < E;
         e += gridDim.x * blockDim.x)
        atomicAdd(&cnt[ei[E + e]], 1);
}

__global__ void scan1k_kernel(int* __restrict__ data, int* __restrict__ bsum, int n)
{
    __shared__ int buf[1024];
    const int gid = blockIdx.x * 1024 + threadIdx.x;
    int v = (gid < n) ? data[gid] : 0;
    buf[threadIdx.x] = v;
    __syncthreads();
    for (int off = 1; off < 1024; off <<= 1) {
        int t = (threadIdx.x >= off) ? buf[threadIdx.x - off] : 0;
        __syncthreads();
        buf[threadIdx.x] += t;
        __syncthreads();
    }
    if (gid < n) data[gid] = buf[threadIdx.x] - v;   // exclusive
    if (bsum && threadIdx.x == 1023) bsum[blockIdx.x] = buf[1023];
}

__global__ void scan_add_kernel(int* __restrict__ data, const int* __restrict__ bsum,
                                int* __restrict__ cursor, int n)
{
    const int gid = blockIdx.x * 1024 + threadIdx.x;
    if (gid < n) {
        int v = data[gid] + bsum[blockIdx.x];
        data[gid] = v;
        cursor[gid] = v;
    }
}

__global__ void scatter_kernel(const int* __restrict__ ei, const float* __restrict__ ew,
                               const float4* __restrict__ ea, int* __restrict__ cursor,
                               float4* __restrict__ rec, int E)
{
    for (int e = blockIdx.x * blockDim.x + threadIdx.x; e < E;
         e += gridDim.x * blockDim.x) {
        int d = ei[E + e];
        int p = atomicAdd(&cursor[d], 1);
        float4 r0;
        r0.x = ew[e];
        r0.y = __int_as_float(ei[e]);
        r0.z = __int_as_float(d);
        r0.w = 0.f;
        rec[(size_t)p * 2]     = r0;
        rec[(size_t)p * 2 + 1] = ea[e];
    }
}

// ---------------------------------------------------------------------------
// Edge kernel: 1024 threads / 16 waves, 64 dst-sorted edges/tile, 1 block/CU.
// Wave w owns nt=w (cols [16w,16w+16)), rbf k-slice [8w,8w+8), flush rows
// [4w,4w+4). Per-wave state: bfrag 16 + acc 16 + gx/xjr 8 regs -> total/wave
// (incl MFMA acc) <= 128 -> 4 waves/SIMD from ONE block (R7-R10 analysis:
// 2-block co-residency fails at arch+acc > 128; 16-wave single block avoids
// needing it). bfrag stays persistent -> no vmcnt-FIFO wait on prev atomics.
// LDS 48KB: sRbf 16KB + sSS 32KB.
// ---------------------------------------------------------------------------
__global__ __launch_bounds__(1024)
void edge_mfma_kernel(
    const unsigned short* __restrict__ xsb,   // bf16 x_src (N,128)
    const float4* __restrict__ rec,           // 32B records, dst-sorted
    const short* __restrict__ pWd, const float* __restrict__ bd,
    const float* __restrict__ Mb, const float* __restrict__ be,
    __half2* __restrict__ agg, int E, int ntiles,
    float rs, float rstep, float rbeta)
{
    __shared__ short sRbf[64 * 128];   // bf16, swizzled [edge][k], 16KB
    __shared__ __half sSS[64 * 256];   // fp16, swizzled [edge][col], 32KB

    const int t = threadIdx.x;
    const int lane = t & 63;
    const int w = t >> 6;          // 0..15
    const int l15 = lane & 15;
    const int l4 = lane >> 4;

    // --- per-block constants (persistent) ---
    short8_t bfrag[4];             // [kk], nt = w  (16 VGPR)
    #pragma unroll
    for (int kk = 0; kk < 4; ++kk)
        bfrag[kk] = *(const short8_t*)&pWd[((kk * 16 + w) * 64 + lane) * 8];
    const float bdv = bd[w * 16 + l15];
    const float be0 = be[2 * lane], be1 = be[2 * lane + 1];
    float ma0[4], ma1[4];
    #pragma unroll
    for (int a = 0; a < 4; ++a) {
        ma0[a] = Mb[a * 128 + 2 * lane];
        ma1[a] = Mb[a * 128 + 2 * lane + 1];
    }

    const int stride = gridDim.x;
    int tile = blockIdx.x;
    if (tile >= ntiles) return;

    // ---- prologue: record (lane = edge) + gathers for first tile ----
    float ew_c; int src_c, dst_c; float4 ea_c;
    {
        int eL = (tile << 6) + lane;
        int ec = eL < E ? eL : E - 1;
        float4 r0 = rec[(size_t)ec * 2];
        float4 r1 = rec[(size_t)ec * 2 + 1];
        ew_c = r0.x;
        src_c = __float_as_int(r0.y);
        dst_c = (eL < E) ? __float_as_int(r0.z) : -1;
        ea_c = r1;
    }
    unsigned int gx[4];
    #pragma unroll
    for (int r = 0; r < 4; ++r) {
        int srn = __shfl(src_c, 4 * w + r);
        gx[r] = *(const unsigned int*)&xsb[(size_t)srn * 128 + lane * 2];
    }

    for (; tile < ntiles; tile += stride) {
        // ---- phase A: rbf -> sRbf (k-slice [8w,8w+8)), xj -> regs ----
        const float edv = __expf(-ew_c);
        const float dcc = fminf(ew_c, 5.0f);
        const float cutv = 0.5f * (__cosf(dcc * 0.62831853071795864769f) + 1.0f);
        {
            short8_t v;
            #pragma unroll
            for (int j = 0; j < 8; ++j) {
                float mean = rs + (float)(w * 8 + j) * rstep;
                float diff = edv - mean;
                v[j] = f2bs(cutv * __expf(-rbeta * diff * diff));
            }
            *(short8_t*)((char*)sRbf + lane * 256 + ((w * 16) ^ ((lane & 7) << 4))) = v;
        }
        unsigned int xjr[4];
        #pragma unroll
        for (int r = 0; r < 4; ++r) {
            int e = 4 * w + r;
            float ea0 = __shfl(ea_c.x, e), ea1 = __shfl(ea_c.y, e);
            float ea2 = __shfl(ea_c.z, e), ea3 = __shfl(ea_c.w, e);
            unsigned int g = gx[r];
            float x0 = bs2f(g & 0xffffu), x1 = bs2f(g >> 16);
            float o0 = x0 + be0 + ea0 * ma0[0] + ea1 * ma0[1] + ea2 * ma0[2] + ea3 * ma0[3];
            float o1 = x1 + be1 + ea0 * ma1[0] + ea1 * ma1[1] + ea2 * ma1[2] + ea3 * ma1[3];
            xjr[r] = pack2bf(o0, o1);
        }

        lds_barrier();   // bar1: sRbf visible (also fences prev-tile sSS reads)

        // ---- phase B ----
        const int ntile = tile + stride;
        const bool has_next = ntile < ntiles;
        float ew_n = 0.f; int src_n = 0, dst_n = -1;
        float4 ea_n = {0.f, 0.f, 0.f, 0.f};
        if (has_next) {   // issue next-tile record load before any atomics
            int eL = (ntile << 6) + lane;
            int ec = eL < E ? eL : E - 1;
            float4 r0 = rec[(size_t)ec * 2];
            float4 r1 = rec[(size_t)ec * 2 + 1];
            ew_n = r0.x;
            src_n = __float_as_int(r0.y);
            dst_n = (eL < E) ? __float_as_int(r0.z) : -1;
            ea_n = r1;
        }
        __builtin_amdgcn_sched_barrier(0);   // pin prefetch issue before GEMM

        // GEMM: ss(64 x 16 cols/wave) = rbf(64x128) @ Wd[:, nt=w]
        f32x4 acc[4];
        #pragma unroll
        for (int m = 0; m < 4; ++m) acc[m] = (f32x4){0.f, 0.f, 0.f, 0.f};
        #pragma unroll
        for (int kk = 0; kk < 4; ++kk) {
            short8_t af[4];
            #pragma unroll
            for (int m = 0; m < 4; ++m) {
                int row = m * 16 + l15;
                int byte = row * 256 + ((kk * 64 + l4 * 16) ^ ((row & 7) << 4));
                af[m] = *(const short8_t*)((const char*)sRbf + byte);
            }
            #pragma unroll
            for (int m = 0; m < 4; ++m)
                acc[m] = __builtin_amdgcn_mfma_f32_16x16x32_bf16(
                    af[m], bfrag[kk], acc[m], 0, 0, 0);
        }

        // ss = acc + bd -> sSS fp16 (swizzled [edge][col]), col = w*16+l15
        {
            const int col2 = (w * 16 + l15) * 2;
            #pragma unroll
            for (int m = 0; m < 4; ++m)
                #pragma unroll
                for (int r = 0; r < 4; ++r) {
                    int row = m * 16 + l4 * 4 + r;
                    int byte = row * 512 + (col2 ^ ((row & 7) << 4));
                    *(__half*)((char*)sSS + byte) = __float2half(acc[m][r] + bdv);
                }
        }

        // issue next-tile gathers (acc dead; still before atomics)
        if (has_next) {
            #pragma unroll
            for (int r = 0; r < 4; ++r) {
                int srn = __shfl(src_n, 4 * w + r);
                gx[r] = *(const unsigned int*)&xsb[(size_t)srn * 128 + lane * 2];
            }
        }
        const int dst_f = dst_c;
        ew_c = ew_n; src_c = src_n; dst_c = dst_n; ea_c = ea_n;

        lds_barrier();   // bar2: sSS visible; sRbf GEMM reads done

        // ---- phase C: segmented run-reduce flush (rows 4w..4w+4, dst-sorted) ----
        {
            float a0 = 0.f, a1 = 0.f;
            int rdst = __shfl(dst_f, 4 * w);
            #pragma unroll
            for (int r = 0; r < 4; ++r) {
                int e = 4 * w + r;
                unsigned int sc = *(const unsigned int*)
                    ((const char*)sSS + e * 512 + ((lane * 4) ^ ((e & 7) << 4)));
                unsigned int sh = *(const unsigned int*)
                    ((const char*)sSS + e * 512 + ((256 + lane * 4) ^ ((e & 7) << 4)));
                float2 scf = __half22float2(*(const __half2*)&sc);
                float2 shf = __half22float2(*(const __half2*)&sh);
                unsigned int g = xjr[r];
                float x0 = bs2f(g & 0xffffu), x1 = bs2f(g >> 16);
                float m0 = fmaxf(fmaf(x0, scf.x, shf.x), 0.0f);
                float m1 = fmaxf(fmaf(x1, scf.y, shf.y), 0.0f);
                int d = __shfl(dst_f, e);
                if (d != rdst) {
                    if (rdst >= 0) {
                        __half2 hv = __floats2half2_rn(a0, a1);
                        unsigned int hb;
                        __builtin_memcpy(&hb, &hv, 4);
                        if (hb)
                            unsafeAtomicAdd(agg + (size_t)rdst * 64 + lane, hv);
                    }
                    a0 = 0.f; a1 = 0.f; rdst = d;
                }
                a0 += m0; a1 += m1;
            }
            if (rdst >= 0) {
                __half2 hv = __floats2half2_rn(a0, a1);
                unsigned int hb;
                __builtin_memcpy(&hb, &hv, 4);
                if (hb)
                    unsafeAtomicAdd(agg + (size_t)rdst * 64 + lane, hv);
            }
        }
    }
}

// ---------------------------------------------------------------------------
// Node kernel (persistent): out = relu((agg+x)@W1+b1)@W2+b2 (+prev, relu opt)
// Weights reloaded per kk from L2-hot packed arrays (no 64 persistent regs)
// -> arch+acc <= 128 -> 4 blocks/CU.
// ---------------------------------------------------------------------------
__global__ __launch_bounds__(256, 2)
void node_mfma_kernel(
    const __half2* __restrict__ agg,
    const float* __restrict__ xdf, const unsigned short* __restrict__ xdb,
    const short* __restrict__ pW1, const float* __restrict__ b1,
    const short* __restrict__ pW2, const float* __restrict__ b2,
    float* __restrict__ outf, unsigned short* __restrict__ outb,
    int N, int ntiles, int accumulate, int relu_out)
{
    __shared__ short sA[64 * 128];
    __shared__ short sH[64 * 128];

    const int t = threadIdx.x;
    const int lane = t & 63;
    const int w = t >> 6;
    const int l15 = lane & 15;
    const int l4 = lane >> 4;

    float b1v[2], b2v[2];
    #pragma unroll
    for (int p = 0; p < 2; ++p) {
        int col = (2 * w + p) * 16 + l15;
        b1v[p] = b1[col];
        b2v[p] = b2[col];
    }

    for (int tile = blockIdx.x; tile < ntiles; tile += gridDim.x) {
        const int n0 = tile << 6;
        // --- stage A = bf16(fp16 agg + x_dst) ---
        #pragma unroll
        for (int i = 0; i < 4; ++i) {
            int idx = i * 256 + t;
            int row = idx >> 4, c8 = idx & 15;
            int gr = n0 + row; if (gr >= N) gr = N - 1;
            union { float4 f; __half2 h[4]; } ar;
            ar.f = ((const float4*)agg)[(size_t)gr * 16 + c8];
            float xv[8];
            if (xdf) {
                float4 x0 = ((const float4*)xdf)[(size_t)gr * 32 + c8 * 2];
                float4 x1 = ((const float4*)xdf)[(size_t)gr * 32 + c8 * 2 + 1];
                xv[0] = x0.x; xv[1] = x0.y; xv[2] = x0.z; xv[3] = x0.w;
                xv[4] = x1.x; xv[5] = x1.y; xv[6] = x1.z; xv[7] = x1.w;
            } else {
                uint4 xr = ((const uint4*)xdb)[(size_t)gr * 16 + c8];
                xv[0] = bs2f(xr.x & 0xffffu); xv[1] = bs2f(xr.x >> 16);
                xv[2] = bs2f(xr.y & 0xffffu); xv[3] = bs2f(xr.y >> 16);
                xv[4] = bs2f(xr.z & 0xffffu); xv[5] = bs2f(xr.z >> 16);
                xv[6] = bs2f(xr.w & 0xffffu); xv[7] = bs2f(xr.w >> 16);
            }
            short8_t v;
            #pragma unroll
            for (int j = 0; j < 4; ++j) {
                float2 a2 = __half22float2(ar.h[j]);
                v[2 * j]     = f2bs(a2.x + xv[2 * j]);
                v[2 * j + 1] = f2bs(a2.y + xv[2 * j + 1]);
            }
            int byte = row * 256 + ((c8 * 16) ^ ((row & 7) << 4));
            *(short8_t*)((char*)sA + byte) = v;
        }
        lds_barrier();

        // --- GEMM1 (weights reloaded per kk) ---
        f32x4 acc[4][2];
        #pragma unroll
        for (int m = 0; m < 4; ++m) {
            acc[m][0] = (f32x4){0.f, 0.f, 0.f, 0.f};
            acc[m][1] = (f32x4){0.f, 0.f, 0.f, 0.f};
        }
        #pragma unroll
        for (int kk = 0; kk < 4; ++kk) {
            short8_t wf[2];
            #pragma unroll
            for (int p = 0; p < 2; ++p)
                wf[p] = *(const short8_t*)&pW1[((kk * 8 + 2 * w + p) * 64 + lane) * 8];
            short8_t af[4];
            #pragma unroll
            for (int m = 0; m < 4; ++m) {
                int row = m * 16 + l15;
                int byte = row * 256 + ((kk * 64 + l4 * 16) ^ ((row & 7) << 4));
                af[m] = *(const short8_t*)((const char*)sA + byte);
            }
            #pragma unroll
            for (int m = 0; m < 4; ++m)
                #pragma unroll
                for (int p = 0; p < 2; ++p)
                    acc[m][p] = __builtin_amdgcn_mfma_f32_16x16x32_bf16(
                        af[m], wf[p], acc[m][p], 0, 0, 0);
        }
        #pragma unroll
        for (int m = 0; m < 4; ++m)
            #pragma unroll
            for (int p = 0; p < 2; ++p) {
                int col = (2 * w + p) * 16 + l15;
                #pragma unroll
                for (int r = 0; r < 4; ++r) {
                    int row = m * 16 + l4 * 4 + r;
                    short hs = f2bs(fmaxf(acc[m][p][r] + b1v[p], 0.f));
                    int byte = row * 256 + ((col * 2) ^ ((row & 7) << 4));
                    *(short*)((char*)sH + byte) = hs;
                }
            }
        lds_barrier();

        // --- GEMM2 ---
        f32x4 acc2[4][2];
        #pragma unroll
        for (int m = 0; m < 4; ++m) {
            acc2[m][0] = (f32x4){0.f, 0.f, 0.f, 0.f};
            acc2[m][1] = (f32x4){0.f, 0.f, 0.f, 0.f};
        }
        #pragma unroll
        for (int kk = 0; kk < 4; ++kk) {
            short8_t wf[2];
            #pragma unroll
            for (int p = 0; p < 2; ++p)
                wf[p] = *(const short8_t*)&pW2[((kk * 8 + 2 * w + p) * 64 + lane) * 8];
            short8_t af[4];
            #pragma unroll
            for (int m = 0; m < 4; ++m) {
                int row = m * 16 + l15;
                int byte = row * 256 + ((kk * 64 + l4 * 16) ^ ((row & 7) << 4));
                af[m] = *(const short8_t*)((const char*)sH + byte);
            }
            #pragma unroll
            for (int m = 0; m < 4; ++m)
                #pragma unroll
                for (int p = 0; p < 2; ++p)
                    acc2[m][p] = __builtin_amdgcn_mfma_f32_16x16x32_bf16(
                        af[m], wf[p], acc2[m][p], 0, 0, 0);
        }
        // --- epilogue ---
        #pragma unroll
        for (int m = 0; m < 4; ++m)
            #pragma unroll
            for (int p = 0; p < 2; ++p) {
                int col = (2 * w + p) * 16 + l15;
                #pragma unroll
                for (int r = 0; r < 4; ++r) {
                    int row = n0 + m * 16 + l4 * 4 + r;
                    if (row < N) {
                        float v = acc2[m][p][r] + b2v[p];
                        if (outf) {
                            float* op = &outf[(size_t)row * 128 + col];
                            if (accumulate) v += *op;
                            if (relu_out) v = fmaxf(v, 0.f);
                            *op = v;
                        } else {
                            unsigned short* op = &outb[(size_t)row * 128 + col];
                            if (accumulate) v += bs2f((unsigned int)*op);
                            if (relu_out) v = fmaxf(v, 0.f);
                            *op = (unsigned short)f2bs(v);
                        }
                    }
                }
            }
    }
}

// ---------------------------------------------------------------------------
extern "C" void kernel_launch(void* const* d_in, const int* in_sizes, int n_in,
                              void* d_out, int out_size, void* d_ws, size_t ws_size,
                              hipStream_t stream)
{
    const float* x_lig   = (const float*)d_in[0];
    const float* x_pock  = (const float*)d_in[1];
    const int*   ei_bond = (const int*)d_in[2];
    const float* ew_bond = (const float*)d_in[3];
    const float* ea_bond = (const float*)d_in[4];
    const int*   ei_lp   = (const int*)d_in[5];
    const float* ew_lp   = (const float*)d_in[6];
    const float* ea_lp   = (const float*)d_in[7];
    const int*   ei_pl   = (const int*)d_in[8];
    const float* ew_pl   = (const float*)d_in[9];
    const float* ea_pl   = (const float*)d_in[10];
    const float* W0 = (const float*)d_in[11];
    const float* Wd = (const float*)d_in[12];
    const float* bd = (const float*)d_in[13];
    const float* We = (const float*)d_in[14];
    const float* be = (const float*)d_in[15];
    const float* W1 = (const float*)d_in[16];
    const float* b1 = (const float*)d_in[17];
    const float* W2 = (const float*)d_in[18];
    const float* b2 = (const float*)d_in[19];

    const int H = 128;
    const int N = in_sizes[0] / H;
    const int E_bond = in_sizes[3];
    const int E_lp   = in_sizes[6];
    const int E_pl   = in_sizes[9];

    // ---- workspace layout (256B-aligned bump allocator) ----
    char* wp = (char*)d_ws;
    auto alloc = [&](size_t bytes) -> char* {
        char* r = wp;
        wp += (bytes + 255) & ~(size_t)255;
        return r;
    };
    unsigned short* A   = (unsigned short*)alloc((size_t)N * H * 2);
    unsigned short* Bb  = (unsigned short*)alloc((size_t)N * H * 2);
    unsigned short* C   = (unsigned short*)alloc((size_t)N * H * 2);
    __half*  agg  = (__half*)alloc((size_t)N * H * 2);
    float4*  recB = (float4*)alloc((size_t)E_bond * 32);
    float4*  recL = (float4*)alloc((size_t)E_lp * 32);
    float4*  recP = (float4*)alloc((size_t)E_pl * 32);
    short*   pWd  = (short*)alloc(6 * 32768 * 2);
    short*   pW1s = (short*)alloc(6 * 16384 * 2);
    short*   pW2s = (short*)alloc(6 * 16384 * 2);
    float*   Mb   = (float*)alloc(6 * 512 * 4);
    int*     cnt    = (int*)alloc((size_t)N * 4);
    int*     cursor = (int*)alloc((size_t)N * 4);
    int*     bsum   = (int*)alloc(1024 * 4);

    float* outL = (float*)d_out;
    float* outP = outL + (size_t)N * H;

    const int capE = 256;        // 1024-thread blocks, 1 per CU
    const int capN = 4 * 256;    // 256-thread blocks, 4 per CU target

    tobf16_kernel<<<512, 256, 0, stream>>>(x_lig, x_pock, A, Bb, N * H / 4);
    pack_kernel<<<256, 256, 0, stream>>>(Wd, W1, W2, W0, We, pWd, pW1s, pW2s, Mb);

    // ---- dst-sort the three edge sets into packed records ----
    const int nb = (N + 1023) / 1024;
    auto sortset = [&](const int* ei_, const float* ew_, const float* ea_, int E,
                       float4* rec) {
        hipMemsetAsync(cnt, 0, (size_t)N * sizeof(int), stream);
        hist_kernel<<<512, 256, 0, stream>>>(ei_, cnt, E);
        scan1k_kernel<<<nb, 1024, 0, stream>>>(cnt, bsum, N);
        scan1k_kernel<<<1, 1024, 0, stream>>>(bsum, nullptr, nb);
        scan_add_kernel<<<nb, 1024, 0, stream>>>(cnt, bsum, cursor, N);
        scatter_kernel<<<512, 256, 0, stream>>>(ei_, ew_, (const float4*)ea_,
                                                cursor, rec, E);
    };
    sortset(ei_bond, ew_bond, ea_bond, E_bond, recB);
    sortset(ei_lp,   ew_lp,   ea_lp,   E_lp,   recL);
    sortset(ei_pl,   ew_pl,   ea_pl,   E_pl,   recP);

    const double start_d = exp(-5.0);
    const float rs    = (float)start_d;
    const float rstep = (float)((1.0 - start_d) / 127.0);
    const float rbeta = (float)std::pow(2.0 / 128.0 * (1.0 - start_d), -2.0);

    auto conv = [&](const unsigned short* src,
                    const float* xdf, const unsigned short* xdb,
                    const float4* rec, int E,
                    int l, int tt, float* outf, unsigned short* outb,
                    int accum, int relu) {
        hipMemsetAsync(agg, 0, (size_t)N * H * sizeof(__half), stream);
        const int lt = l * 3 + tt;
        const int ntE = (E + 63) / 64;
        const int gE = ntE < capE ? ntE : capE;
        edge_mfma_kernel<<<gE, 1024, 0, stream>>>(
            src, rec,
            pWd + (size_t)lt * 32768, bd + (size_t)lt * 256,
            Mb + (size_t)lt * 512, be + (size_t)lt * 128,
            (__half2*)agg, E, ntE, rs, rstep, rbeta);
        const int ntN = (N + 63) / 64;
        const int gN = ntN < capN ? ntN : capN;
        node_mfma_kernel<<<gN, 256, 0, stream>>>(
            (const __half2*)agg, xdf, xdb,
            pW1s + (size_t)lt * 16384, b1 + (size_t)lt * 128,
            pW2s + (size_t)lt * 16384, b2 + (size_t)lt * 128,
            outf, outb, N, ntN, accum, relu);
    };

    // layer 0 (order matters: A is overwritten by bond0's node after lp0+bond0 edges read it)
    conv(A,  x_pock, nullptr, recL, E_lp,   0, 1, nullptr, C, 0, 1);
    conv(A,  x_lig,  nullptr, recB, E_bond, 0, 0, nullptr, A, 0, 0);
    conv(Bb, x_lig,  nullptr, recP, E_pl,   0, 2, nullptr, A, 1, 1);
    // layer 1: lig_bf = A, pock_bf = C
    conv(A, nullptr, A, recB, E_bond, 1, 0, outL, nullptr, 0, 0);
    conv(C, nullptr, A, recP, E_pl,   1, 2, outL, nullptr, 1, 0);
    conv(A, nullptr, C, recL, E_lp,   1, 1, outP, nullptr, 0, 0);
}

// Round 12
// 849.743 us; speedup vs baseline: 1.1942x; 1.1942x over previous
//
#include <hip/hip_runtime.h>
#include <hip/hip_bf16.h>
#include <hip/hip_fp16.h>
#include <cmath>

typedef __attribute__((ext_vector_type(8))) short short8_t;
typedef __attribute__((ext_vector_type(4))) float f32x4;

static __device__ __forceinline__ short f2bs(float f) {
    union { __hip_bfloat16 h; short s; } u;
    u.h = __float2bfloat16(f);
    return u.s;
}
static __device__ __forceinline__ float bs2f(unsigned int us) {
    union { float f; unsigned int i; } u;
    u.i = us << 16;
    return u.f;
}
static __device__ __forceinline__ unsigned int pack2bf(float a, float b) {
    return (unsigned int)(unsigned short)f2bs(a) |
           ((unsigned int)(unsigned short)f2bs(b) << 16);
}
// Barrier that waits only on LDS ops (lgkmcnt), NOT vmem.
static __device__ __forceinline__ void lds_barrier() {
    asm volatile("s_waitcnt lgkmcnt(0)\n\ts_barrier" ::: "memory");
}

// ---------------------------------------------------------------------------
// Pack kernel: Wd/W1/W2 -> bf16 MFMA B-fragment order; M = W0t @ We (fp32).
// ---------------------------------------------------------------------------
__global__ void pack_kernel(const float* __restrict__ Wd,
                            const float* __restrict__ W1,
                            const float* __restrict__ W2,
                            const float* __restrict__ W0,
                            const float* __restrict__ We,
                            short* __restrict__ pWd,
                            short* __restrict__ pW1,
                            short* __restrict__ pW2,
                            float* __restrict__ Mb)
{
    const int tid = blockIdx.x * blockDim.x + threadIdx.x;
    const int stride = gridDim.x * blockDim.x;
    for (int i = tid; i < 6 * 32768; i += stride) {
        int c = i >> 15, rem = i & 32767;
        int f = rem >> 9, l = (rem >> 3) & 63, j = rem & 7;
        int kk = f >> 4, nt = f & 15;
        int k = kk * 32 + (l >> 4) * 8 + j;
        int n = nt * 16 + (l & 15);
        pWd[i] = f2bs(Wd[(size_t)c * 32768 + k * 256 + n]);
    }
    for (int i = tid; i < 6 * 16384; i += stride) {
        int c = i >> 14, rem = i & 16383;
        int f = rem >> 9, l = (rem >> 3) & 63, j = rem & 7;
        int kk = f >> 3, nt = f & 7;
        int k = kk * 32 + (l >> 4) * 8 + j;
        int n = nt * 16 + (l & 15);
        pW1[i] = f2bs(W1[(size_t)c * 16384 + k * 128 + n]);
        pW2[i] = f2bs(W2[(size_t)c * 16384 + k * 128 + n]);
    }
    for (int i = tid; i < 6 * 512; i += stride) {
        int c = i >> 9, rem = i & 511;
        int a = rem >> 7, h = rem & 127;
        int t = c % 3;
        float m = 0.f;
        #pragma unroll
        for (int j = 0; j < 4; ++j)
            m = fmaf(W0[t * 16 + a * 4 + j], We[(size_t)c * 512 + j * 128 + h], m);
        Mb[i] = m;
    }
}

// ---------------------------------------------------------------------------
// Convert fp32 -> bf16 (two arrays)
// ---------------------------------------------------------------------------
__global__ void tobf16_kernel(const float* __restrict__ a, const float* __restrict__ b,
                              unsigned short* __restrict__ oa, unsigned short* __restrict__ ob,
                              int n4)
{
    int i = blockIdx.x * blockDim.x + threadIdx.x;
    const int stride = gridDim.x * blockDim.x;
    for (; i < n4; i += stride) {
        float4 va = ((const float4*)a)[i];
        uint2 pa; pa.x = pack2bf(va.x, va.y); pa.y = pack2bf(va.z, va.w);
        ((uint2*)oa)[i] = pa;
        float4 vb = ((const float4*)b)[i];
        uint2 pb; pb.x = pack2bf(vb.x, vb.y); pb.y = pack2bf(vb.z, vb.w);
        ((uint2*)ob)[i] = pb;
    }
}

// ---------------------------------------------------------------------------
// Counting-sort kernels. Sorted edges packed into ONE 16B record
//   rec[p] = { src, dst, ea01(bf16x2), ea23(bf16x2) }  + separate ewp[p].
// (R10 lesson: 4-array scatter = 4 random lines/edge, ~2x the cost.)
// ---------------------------------------------------------------------------
__global__ void hist_kernel(const int* __restrict__ ei, int* __restrict__ cnt, int E)
{
    for (int e = blockIdx.x * blockDim.x + threadIdx.x; e < E;
         e += gridDim.x * blockDim.x)
        atomicAdd(&cnt[ei[E + e]], 1);
}

__global__ void scan1k_kernel(int* __restrict__ data, int* __restrict__ bsum, int n)
{
    __shared__ int buf[1024];
    const int gid = blockIdx.x * 1024 + threadIdx.x;
    int v = (gid < n) ? data[gid] : 0;
    buf[threadIdx.x] = v;
    __syncthreads();
    for (int off = 1; off < 1024; off <<= 1) {
        int t = (threadIdx.x >= off) ? buf[threadIdx.x - off] : 0;
        __syncthreads();
        buf[threadIdx.x] += t;
        __syncthreads();
    }
    if (gid < n) data[gid] = buf[threadIdx.x] - v;   // exclusive
    if (bsum && threadIdx.x == 1023) bsum[blockIdx.x] = buf[1023];
}

__global__ void scan_add_kernel(int* __restrict__ data, const int* __restrict__ bsum,
                                int* __restrict__ cursor, int n)
{
    const int gid = blockIdx.x * 1024 + threadIdx.x;
    if (gid < n) {
        int v = data[gid] + bsum[blockIdx.x];
        data[gid] = v;
        cursor[gid] = v;
    }
}

__global__ void scatter_kernel(const int* __restrict__ ei, const float* __restrict__ ew,
                               const float4* __restrict__ ea, int* __restrict__ cursor,
                               uint4* __restrict__ rec, float* __restrict__ ewp, int E)
{
    for (int e = blockIdx.x * blockDim.x + threadIdx.x; e < E;
         e += gridDim.x * blockDim.x) {
        int d = ei[E + e];
        int p = atomicAdd(&cursor[d], 1);
        float4 a = ea[e];
        uint4 r;
        r.x = (unsigned int)ei[e];
        r.y = (unsigned int)d;
        r.z = pack2bf(a.x, a.y);
        r.w = pack2bf(a.z, a.w);
        rec[p] = r;
        ewp[p] = ew[e];
    }
}

// ---------------------------------------------------------------------------
// Edge kernel (persistent, 512 threads / 8 waves, 64 dst-SORTED edges/tile).
// Wave w owns output cols [32w,32w+32) AND flush rows [8w,8w+8).
// Flush: dst-sorted rows -> fp32 run-reduce over window 8, one fp16x2 atomic
// per distinct dst. (R11 lesson: 16-wave/window-4 variant regressed — more
// atomics + barrier convoy; 8-wave/window-8 at 21% occ is the proven best.)
// ---------------------------------------------------------------------------
__global__ __launch_bounds__(512, 2)
void edge_mfma_kernel(
    const unsigned short* __restrict__ xsb,   // bf16 x_src (N,128)
    const uint4* __restrict__ rec,            // {src,dst,ea01,ea23} dst-sorted
    const float* __restrict__ ewp,            // dst-sorted edge weights
    const short* __restrict__ pWd, const float* __restrict__ bd,
    const float* __restrict__ Mb, const float* __restrict__ be,
    __half2* __restrict__ agg, int E, int ntiles,
    float rs, float rstep, float rbeta)
{
    __shared__ short sRbf[64 * 128];   // bf16, swizzled [edge][k], 16KB
    __shared__ __half sSS[64 * 256];   // fp16, swizzled [edge][col], 32KB

    const int t = threadIdx.x;
    const int lane = t & 63;
    const int w = t >> 6;          // 0..7
    const int l15 = lane & 15;
    const int l4 = lane >> 4;

    short8_t bfrag[4][2];          // [kk][i], nt = 2w+i
    #pragma unroll
    for (int kk = 0; kk < 4; ++kk)
        #pragma unroll
        for (int i = 0; i < 2; ++i)
            bfrag[kk][i] = *(const short8_t*)&pWd[((kk * 16 + 2 * w + i) * 64 + lane) * 8];
    float bdv[2];
    #pragma unroll
    for (int i = 0; i < 2; ++i) bdv[i] = bd[(2 * w + i) * 16 + l15];
    const float be0 = be[2 * lane], be1 = be[2 * lane + 1];
    float ma0[4], ma1[4];
    #pragma unroll
    for (int a = 0; a < 4; ++a) {
        ma0[a] = Mb[a * 128 + 2 * lane];
        ma1[a] = Mb[a * 128 + 2 * lane + 1];
    }

    const int stride = gridDim.x;
    int tile = blockIdx.x;
    if (tile >= ntiles) return;

    // ---- prologue: record (lane = edge) + gathers for first tile ----
    float ew_c; int src_c, dst_c; unsigned int ea01_c, ea23_c;
    unsigned int gx[8];
    {
        int eL = (tile << 6) + lane;
        int ec = eL < E ? eL : E - 1;
        uint4 r = rec[ec];
        ew_c = ewp[ec];
        src_c = (int)r.x;
        dst_c = (eL < E) ? (int)r.y : -1;
        ea01_c = r.z; ea23_c = r.w;
        #pragma unroll
        for (int rr = 0; rr < 8; ++rr) {
            int srn = __shfl(src_c, 8 * w + rr);
            gx[rr] = *(const unsigned int*)&xsb[(size_t)srn * 128 + lane * 2];
        }
    }

    for (; tile < ntiles; tile += stride) {
        // ---- phase A: rbf -> sRbf (k-slice [32w,32w+32)... 8 waves x 16), xj -> regs ----
        const float edv = __expf(-ew_c);
        const float dcc = fminf(ew_c, 5.0f);
        const float cutv = 0.5f * (__cosf(dcc * 0.62831853071795864769f) + 1.0f);
        {
            char* base = (char*)sRbf + lane * 256;
            #pragma unroll
            for (int c = 0; c < 2; ++c) {
                short8_t v;
                #pragma unroll
                for (int j = 0; j < 8; ++j) {
                    float mean = rs + (float)(w * 16 + c * 8 + j) * rstep;
                    float diff = edv - mean;
                    v[j] = f2bs(cutv * __expf(-rbeta * diff * diff));
                }
                *(short8_t*)(base + ((w * 32 + c * 16) ^ ((lane & 7) << 4))) = v;
            }
        }
        unsigned int xjr[8];
        #pragma unroll
        for (int r = 0; r < 8; ++r) {
            unsigned int a01 = __shfl(ea01_c, 8 * w + r);
            unsigned int a23 = __shfl(ea23_c, 8 * w + r);
            float ea0 = bs2f(a01 & 0xffffu), ea1 = bs2f(a01 >> 16);
            float ea2 = bs2f(a23 & 0xffffu), ea3 = bs2f(a23 >> 16);
            unsigned int g = gx[r];
            float x0 = bs2f(g & 0xffffu), x1 = bs2f(g >> 16);
            float o0 = x0 + be0 + ea0 * ma0[0] + ea1 * ma0[1] + ea2 * ma0[2] + ea3 * ma0[3];
            float o1 = x1 + be1 + ea0 * ma1[0] + ea1 * ma1[1] + ea2 * ma1[2] + ea3 * ma1[3];
            xjr[r] = pack2bf(o0, o1);
        }

        lds_barrier();   // bar1: sRbf visible (also fences prev-tile sSS reads)

        // ---- phase B ----
        const int ntile = tile + stride;
        const bool has_next = ntile < ntiles;
        float ew_n = 0.f; int src_n = 0, dst_n = -1;
        unsigned int ea01_n = 0, ea23_n = 0;
        if (has_next) {   // issue next-tile record load before any atomics
            int eL = (ntile << 6) + lane;
            int ec = eL < E ? eL : E - 1;
            uint4 r = rec[ec];
            ew_n = ewp[ec];
            src_n = (int)r.x;
            dst_n = (eL < E) ? (int)r.y : -1;
            ea01_n = r.z; ea23_n = r.w;
        }
        __builtin_amdgcn_sched_barrier(0);   // pin prefetch issue before GEMM

        // GEMM: ss(64 x 32cols/wave) = rbf(64x128) @ Wd-slice
        f32x4 acc[4][2];
        #pragma unroll
        for (int m = 0; m < 4; ++m) {
            acc[m][0] = (f32x4){0.f, 0.f, 0.f, 0.f};
            acc[m][1] = (f32x4){0.f, 0.f, 0.f, 0.f};
        }
        #pragma unroll
        for (int kk = 0; kk < 4; ++kk) {
            short8_t af[4];
            #pragma unroll
            for (int m = 0; m < 4; ++m) {
                int row = m * 16 + l15;
                int byte = row * 256 + ((kk * 64 + l4 * 16) ^ ((row & 7) << 4));
                af[m] = *(const short8_t*)((const char*)sRbf + byte);
            }
            #pragma unroll
            for (int m = 0; m < 4; ++m)
                #pragma unroll
                for (int i = 0; i < 2; ++i)
                    acc[m][i] = __builtin_amdgcn_mfma_f32_16x16x32_bf16(
                        af[m], bfrag[kk][i], acc[m][i], 0, 0, 0);
        }

        // ss = acc + bd -> sSS fp16 (swizzled [edge][col])
        #pragma unroll
        for (int m = 0; m < 4; ++m)
            #pragma unroll
            for (int i = 0; i < 2; ++i) {
                int col = (2 * w + i) * 16 + l15;
                #pragma unroll
                for (int r = 0; r < 4; ++r) {
                    int row = m * 16 + l4 * 4 + r;
                    int byte = row * 512 + ((col * 2) ^ ((row & 7) << 4));
                    *(__half*)((char*)sSS + byte) = __float2half(acc[m][i][r] + bdv[i]);
                }
            }

        // issue next-tile gathers (acc dead; still before atomics)
        if (has_next) {
            #pragma unroll
            for (int r = 0; r < 8; ++r) {
                int srn = __shfl(src_n, 8 * w + r);
                gx[r] = *(const unsigned int*)&xsb[(size_t)srn * 128 + lane * 2];
            }
        }
        const int dst_f = dst_c;
        ew_c = ew_n; src_c = src_n; dst_c = dst_n; ea01_c = ea01_n; ea23_c = ea23_n;

        lds_barrier();   // bar2: sSS visible; sRbf GEMM reads done

        // ---- phase C: segmented run-reduce flush (rows 8w..8w+8, dst-sorted) ----
        {
            float a0 = 0.f, a1 = 0.f;
            int rdst = __shfl(dst_f, 8 * w);
            #pragma unroll
            for (int r = 0; r < 8; ++r) {
                int e = 8 * w + r;
                unsigned int sc = *(const unsigned int*)
                    ((const char*)sSS + e * 512 + ((lane * 4) ^ ((e & 7) << 4)));
                unsigned int sh = *(const unsigned int*)
                    ((const char*)sSS + e * 512 + ((256 + lane * 4) ^ ((e & 7) << 4)));
                float2 scf = __half22float2(*(const __half2*)&sc);
                float2 shf = __half22float2(*(const __half2*)&sh);
                unsigned int g = xjr[r];
                float x0 = bs2f(g & 0xffffu), x1 = bs2f(g >> 16);
                float m0 = fmaxf(fmaf(x0, scf.x, shf.x), 0.0f);
                float m1 = fmaxf(fmaf(x1, scf.y, shf.y), 0.0f);
                int d = __shfl(dst_f, e);
                if (d != rdst) {
                    if (rdst >= 0) {
                        __half2 hv = __floats2half2_rn(a0, a1);
                        unsigned int hb;
                        __builtin_memcpy(&hb, &hv, 4);
                        if (hb)
                            unsafeAtomicAdd(agg + (size_t)rdst * 64 + lane, hv);
                    }
                    a0 = 0.f; a1 = 0.f; rdst = d;
                }
                a0 += m0; a1 += m1;
            }
            if (rdst >= 0) {
                __half2 hv = __floats2half2_rn(a0, a1);
                unsigned int hb;
                __builtin_memcpy(&hb, &hv, 4);
                if (hb)
                    unsafeAtomicAdd(agg + (size_t)rdst * 64 + lane, hv);
            }
        }
    }
}

// ---------------------------------------------------------------------------
// Node kernel (persistent): out = relu((agg+x)@W1+b1)@W2+b2 (+prev, relu opt)
// Persistent weight frags (R9's proven shape). Zeroes agg in place after
// reading it (replaces the per-conv memset dispatch).
// ---------------------------------------------------------------------------
__global__ __launch_bounds__(256)
void node_mfma_kernel(
    __half2* __restrict__ agg,
    const float* __restrict__ xdf, const unsigned short* __restrict__ xdb,
    const short* __restrict__ pW1, const float* __restrict__ b1,
    const short* __restrict__ pW2, const float* __restrict__ b2,
    float* __restrict__ outf, unsigned short* __restrict__ outb,
    int N, int ntiles, int accumulate, int relu_out)
{
    __shared__ short sA[64 * 128];
    __shared__ short sH[64 * 128];

    const int t = threadIdx.x;
    const int lane = t & 63;
    const int w = t >> 6;
    const int l15 = lane & 15;
    const int l4 = lane >> 4;

    short8_t w1f[4][2], w2f[4][2];
    #pragma unroll
    for (int kk = 0; kk < 4; ++kk)
        #pragma unroll
        for (int p = 0; p < 2; ++p) {
            int nt = 2 * w + p;
            w1f[kk][p] = *(const short8_t*)&pW1[((kk * 8 + nt) * 64 + lane) * 8];
            w2f[kk][p] = *(const short8_t*)&pW2[((kk * 8 + nt) * 64 + lane) * 8];
        }
    float b1v[2], b2v[2];
    #pragma unroll
    for (int p = 0; p < 2; ++p) {
        int col = (2 * w + p) * 16 + l15;
        b1v[p] = b1[col];
        b2v[p] = b2[col];
    }

    const float4 zero4 = {0.f, 0.f, 0.f, 0.f};

    for (int tile = blockIdx.x; tile < ntiles; tile += gridDim.x) {
        const int n0 = tile << 6;
        // --- stage A = bf16(fp16 agg + x_dst); zero agg after read ---
        #pragma unroll
        for (int i = 0; i < 4; ++i) {
            int idx = i * 256 + t;
            int row = idx >> 4, c8 = idx & 15;
            int gr = n0 + row; if (gr >= N) gr = N - 1;
            union { float4 f; __half2 h[4]; } ar;
            ar.f = ((const float4*)agg)[(size_t)gr * 16 + c8];
            ((float4*)agg)[(size_t)gr * 16 + c8] = zero4;   // reset for next conv
            float xv[8];
            if (xdf) {
                float4 x0 = ((const float4*)xdf)[(size_t)gr * 32 + c8 * 2];
                float4 x1 = ((const float4*)xdf)[(size_t)gr * 32 + c8 * 2 + 1];
                xv[0] = x0.x; xv[1] = x0.y; xv[2] = x0.z; xv[3] = x0.w;
                xv[4] = x1.x; xv[5] = x1.y; xv[6] = x1.z; xv[7] = x1.w;
            } else {
                uint4 xr = ((const uint4*)xdb)[(size_t)gr * 16 + c8];
                xv[0] = bs2f(xr.x & 0xffffu); xv[1] = bs2f(xr.x >> 16);
                xv[2] = bs2f(xr.y & 0xffffu); xv[3] = bs2f(xr.y >> 16);
                xv[4] = bs2f(xr.z & 0xffffu); xv[5] = bs2f(xr.z >> 16);
                xv[6] = bs2f(xr.w & 0xffffu); xv[7] = bs2f(xr.w >> 16);
            }
            short8_t v;
            #pragma unroll
            for (int j = 0; j < 4; ++j) {
                float2 a2 = __half22float2(ar.h[j]);
                v[2 * j]     = f2bs(a2.x + xv[2 * j]);
                v[2 * j + 1] = f2bs(a2.y + xv[2 * j + 1]);
            }
            int byte = row * 256 + ((c8 * 16) ^ ((row & 7) << 4));
            *(short8_t*)((char*)sA + byte) = v;
        }
        lds_barrier();

        f32x4 acc[4][2];
        #pragma unroll
        for (int m = 0; m < 4; ++m) {
            acc[m][0] = (f32x4){0.f, 0.f, 0.f, 0.f};
            acc[m][1] = (f32x4){0.f, 0.f, 0.f, 0.f};
        }
        #pragma unroll
        for (int kk = 0; kk < 4; ++kk) {
            short8_t af[4];
            #pragma unroll
            for (int m = 0; m < 4; ++m) {
                int row = m * 16 + l15;
                int byte = row * 256 + ((kk * 64 + l4 * 16) ^ ((row & 7) << 4));
                af[m] = *(const short8_t*)((const char*)sA + byte);
            }
            #pragma unroll
            for (int m = 0; m < 4; ++m)
                #pragma unroll
                for (int p = 0; p < 2; ++p)
                    acc[m][p] = __builtin_amdgcn_mfma_f32_16x16x32_bf16(
                        af[m], w1f[kk][p], acc[m][p], 0, 0, 0);
        }
        #pragma unroll
        for (int m = 0; m < 4; ++m)
            #pragma unroll
            for (int p = 0; p < 2; ++p) {
                int col = (2 * w + p) * 16 + l15;
                #pragma unroll
                for (int r = 0; r < 4; ++r) {
                    int row = m * 16 + l4 * 4 + r;
                    short hs = f2bs(fmaxf(acc[m][p][r] + b1v[p], 0.f));
                    int byte = row * 256 + ((col * 2) ^ ((row & 7) << 4));
                    *(short*)((char*)sH + byte) = hs;
                }
            }
        lds_barrier();

        f32x4 acc2[4][2];
        #pragma unroll
        for (int m = 0; m < 4; ++m) {
            acc2[m][0] = (f32x4){0.f, 0.f, 0.f, 0.f};
            acc2[m][1] = (f32x4){0.f, 0.f, 0.f, 0.f};
        }
        #pragma unroll
        for (int kk = 0; kk < 4; ++kk) {
            short8_t af[4];
            #pragma unroll
            for (int m = 0; m < 4; ++m) {
                int row = m * 16 + l15;
                int byte = row * 256 + ((kk * 64 + l4 * 16) ^ ((row & 7) << 4));
                af[m] = *(const short8_t*)((const char*)sH + byte);
            }
            #pragma unroll
            for (int m = 0; m < 4; ++m)
                #pragma unroll
                for (int p = 0; p < 2; ++p)
                    acc2[m][p] = __builtin_amdgcn_mfma_f32_16x16x32_bf16(
                        af[m], w2f[kk][p], acc2[m][p], 0, 0, 0);
        }
        #pragma unroll
        for (int m = 0; m < 4; ++m)
            #pragma unroll
            for (int p = 0; p < 2; ++p) {
                int col = (2 * w + p) * 16 + l15;
                #pragma unroll
                for (int r = 0; r < 4; ++r) {
                    int row = n0 + m * 16 + l4 * 4 + r;
                    if (row < N) {
                        float v = acc2[m][p][r] + b2v[p];
                        if (outf) {
                            float* op = &outf[(size_t)row * 128 + col];
                            if (accumulate) v += *op;
                            if (relu_out) v = fmaxf(v, 0.f);
                            *op = v;
                        } else {
                            unsigned short* op = &outb[(size_t)row * 128 + col];
                            if (accumulate) v += bs2f((unsigned int)*op);
                            if (relu_out) v = fmaxf(v, 0.f);
                            *op = (unsigned short)f2bs(v);
                        }
                    }
                }
            }
    }
}

// ---------------------------------------------------------------------------
extern "C" void kernel_launch(void* const* d_in, const int* in_sizes, int n_in,
                              void* d_out, int out_size, void* d_ws, size_t ws_size,
                              hipStream_t stream)
{
    const float* x_lig   = (const float*)d_in[0];
    const float* x_pock  = (const float*)d_in[1];
    const int*   ei_bond = (const int*)d_in[2];
    const float* ew_bond = (const float*)d_in[3];
    const float* ea_bond = (const float*)d_in[4];
    const int*   ei_lp   = (const int*)d_in[5];
    const float* ew_lp   = (const float*)d_in[6];
    const float* ea_lp   = (const float*)d_in[7];
    const int*   ei_pl   = (const int*)d_in[8];
    const float* ew_pl   = (const float*)d_in[9];
    const float* ea_pl   = (const float*)d_in[10];
    const float* W0 = (const float*)d_in[11];
    const float* Wd = (const float*)d_in[12];
    const float* bd = (const float*)d_in[13];
    const float* We = (const float*)d_in[14];
    const float* be = (const float*)d_in[15];
    const float* W1 = (const float*)d_in[16];
    const float* b1 = (const float*)d_in[17];
    const float* W2 = (const float*)d_in[18];
    const float* b2 = (const float*)d_in[19];

    const int H = 128;
    const int N = in_sizes[0] / H;
    const int E_bond = in_sizes[3];
    const int E_lp   = in_sizes[6];
    const int E_pl   = in_sizes[9];

    // ---- workspace layout (256B-aligned bump allocator), ~123MB ----
    char* wp = (char*)d_ws;
    auto alloc = [&](size_t bytes) -> char* {
        char* r = wp;
        wp += (bytes + 255) & ~(size_t)255;
        return r;
    };
    unsigned short* A   = (unsigned short*)alloc((size_t)N * H * 2);
    unsigned short* Bb  = (unsigned short*)alloc((size_t)N * H * 2);
    unsigned short* C   = (unsigned short*)alloc((size_t)N * H * 2);
    __half*  agg  = (__half*)alloc((size_t)N * H * 2);
    uint4*   recB = (uint4*)alloc((size_t)E_bond * 16);
    uint4*   recL = (uint4*)alloc((size_t)E_lp * 16);
    uint4*   recP = (uint4*)alloc((size_t)E_pl * 16);
    float*   ewpB = (float*)alloc((size_t)E_bond * 4);
    float*   ewpL = (float*)alloc((size_t)E_lp * 4);
    float*   ewpP = (float*)alloc((size_t)E_pl * 4);
    short*   pWd  = (short*)alloc(6 * 32768 * 2);
    short*   pW1s = (short*)alloc(6 * 16384 * 2);
    short*   pW2s = (short*)alloc(6 * 16384 * 2);
    float*   Mb   = (float*)alloc(6 * 512 * 4);
    int*     cnt    = (int*)alloc((size_t)N * 4);
    int*     cursor = (int*)alloc((size_t)N * 4);
    int*     bsum   = (int*)alloc(1024 * 4);

    float* outL = (float*)d_out;
    float* outP = outL + (size_t)N * H;

    const int capE = 256;        // 1 resident 512-thr block/CU (R10 proven)
    const int capN = 4 * 256;    // R9 proven node grid

    // agg zeroed once here; thereafter each node kernel re-zeroes after read.
    hipMemsetAsync(agg, 0, (size_t)N * H * sizeof(__half), stream);
    tobf16_kernel<<<512, 256, 0, stream>>>(x_lig, x_pock, A, Bb, N * H / 4);
    pack_kernel<<<256, 256, 0, stream>>>(Wd, W1, W2, W0, We, pWd, pW1s, pW2s, Mb);

    // ---- dst-sort the three edge sets into packed 16B records ----
    const int nb = (N + 1023) / 1024;
    auto sortset = [&](const int* ei_, const float* ew_, const float* ea_, int E,
                       uint4* rec, float* ewp) {
        hipMemsetAsync(cnt, 0, (size_t)N * sizeof(int), stream);
        hist_kernel<<<512, 256, 0, stream>>>(ei_, cnt, E);
        scan1k_kernel<<<nb, 1024, 0, stream>>>(cnt, bsum, N);
        scan1k_kernel<<<1, 1024, 0, stream>>>(bsum, nullptr, nb);
        scan_add_kernel<<<nb, 1024, 0, stream>>>(cnt, bsum, cursor, N);
        scatter_kernel<<<512, 256, 0, stream>>>(ei_, ew_, (const float4*)ea_,
                                                cursor, rec, ewp, E);
    };
    sortset(ei_bond, ew_bond, ea_bond, E_bond, recB, ewpB);
    sortset(ei_lp,   ew_lp,   ea_lp,   E_lp,   recL, ewpL);
    sortset(ei_pl,   ew_pl,   ea_pl,   E_pl,   recP, ewpP);

    const double start_d = exp(-5.0);
    const float rs    = (float)start_d;
    const float rstep = (float)((1.0 - start_d) / 127.0);
    const float rbeta = (float)std::pow(2.0 / 128.0 * (1.0 - start_d), -2.0);

    auto conv = [&](const unsigned short* src,
                    const float* xdf, const unsigned short* xdb,
                    const uint4* rec, const float* ewp, int E,
                    int l, int tt, float* outf, unsigned short* outb,
                    int accum, int relu) {
        const int lt = l * 3 + tt;
        const int ntE = (E + 63) / 64;
        const int gE = ntE < capE ? ntE : capE;
        edge_mfma_kernel<<<gE, 512, 0, stream>>>(
            src, rec, ewp,
            pWd + (size_t)lt * 32768, bd + (size_t)lt * 256,
            Mb + (size_t)lt * 512, be + (size_t)lt * 128,
            (__half2*)agg, E, ntE, rs, rstep, rbeta);
        const int ntN = (N + 63) / 64;
        const int gN = ntN < capN ? ntN : capN;
        node_mfma_kernel<<<gN, 256, 0, stream>>>(
            (__half2*)agg, xdf, xdb,
            pW1s + (size_t)lt * 16384, b1 + (size_t)lt * 128,
            pW2s + (size_t)lt * 16384, b2 + (size_t)lt * 128,
            outf, outb, N, ntN, accum, relu);
    };

    // layer 0 (order matters: A is overwritten by bond0's node after lp0+bond0 edges read it)
    conv(A,  x_pock, nullptr, recL, ewpL, E_lp,   0, 1, nullptr, C, 0, 1);
    conv(A,  x_lig,  nullptr, recB, ewpB, E_bond, 0, 0, nullptr, A, 0, 0);
    conv(Bb, x_lig,  nullptr, recP, ewpP, E_pl,   0, 2, nullptr, A, 1, 1);
    // layer 1: lig_bf = A, pock_bf = C
    conv(A, nullptr, A, recB, ewpB, E_bond, 1, 0, outL, nullptr, 0, 0);
    conv(C, nullptr, A, recP, ewpP, E_pl,   1, 2, outL, nullptr, 1, 0);
    conv(A, nullptr, C, recL, ewpL, E_lp,   1, 1, outP, nullptr, 0, 0);
}

// Round 13
// 811.970 us; speedup vs baseline: 1.2497x; 1.0465x over previous
//
#include <hip/hip_runtime.h>
#include <hip/hip_bf16.h>
#include <hip/hip_fp16.h>
#include <cmath>

typedef __attribute__((ext_vector_type(8))) short short8_t;
typedef __attribute__((ext_vector_type(4))) float f32x4;

static __device__ __forceinline__ short f2bs(float f) {
    union { __hip_bfloat16 h; short s; } u;
    u.h = __float2bfloat16(f);
    return u.s;
}
static __device__ __forceinline__ float bs2f(unsigned int us) {
    union { float f; unsigned int i; } u;
    u.i = us << 16;
    return u.f;
}
static __device__ __forceinline__ unsigned int pack2bf(float a, float b) {
    return (unsigned int)(unsigned short)f2bs(a) |
           ((unsigned int)(unsigned short)f2bs(b) << 16);
}
// Barrier that waits only on LDS ops (lgkmcnt), NOT vmem.
static __device__ __forceinline__ void lds_barrier() {
    asm volatile("s_waitcnt lgkmcnt(0)\n\ts_barrier" ::: "memory");
}

// ---------------------------------------------------------------------------
// Pack kernel: Wd/W1/W2 -> bf16 MFMA B-fragment order; M = W0t @ We (fp32).
// ---------------------------------------------------------------------------
__global__ void pack_kernel(const float* __restrict__ Wd,
                            const float* __restrict__ W1,
                            const float* __restrict__ W2,
                            const float* __restrict__ W0,
                            const float* __restrict__ We,
                            short* __restrict__ pWd,
                            short* __restrict__ pW1,
                            short* __restrict__ pW2,
                            float* __restrict__ Mb)
{
    const int tid = blockIdx.x * blockDim.x + threadIdx.x;
    const int stride = gridDim.x * blockDim.x;
    for (int i = tid; i < 6 * 32768; i += stride) {
        int c = i >> 15, rem = i & 32767;
        int f = rem >> 9, l = (rem >> 3) & 63, j = rem & 7;
        int kk = f >> 4, nt = f & 15;
        int k = kk * 32 + (l >> 4) * 8 + j;
        int n = nt * 16 + (l & 15);
        pWd[i] = f2bs(Wd[(size_t)c * 32768 + k * 256 + n]);
    }
    for (int i = tid; i < 6 * 16384; i += stride) {
        int c = i >> 14, rem = i & 16383;
        int f = rem >> 9, l = (rem >> 3) & 63, j = rem & 7;
        int kk = f >> 3, nt = f & 7;
        int k = kk * 32 + (l >> 4) * 8 + j;
        int n = nt * 16 + (l & 15);
        pW1[i] = f2bs(W1[(size_t)c * 16384 + k * 128 + n]);
        pW2[i] = f2bs(W2[(size_t)c * 16384 + k * 128 + n]);
    }
    for (int i = tid; i < 6 * 512; i += stride) {
        int c = i >> 9, rem = i & 511;
        int a = rem >> 7, h = rem & 127;
        int t = c % 3;
        float m = 0.f;
        #pragma unroll
        for (int j = 0; j < 4; ++j)
            m = fmaf(W0[t * 16 + a * 4 + j], We[(size_t)c * 512 + j * 128 + h], m);
        Mb[i] = m;
    }
}

// ---------------------------------------------------------------------------
// Convert fp32 -> bf16 (two arrays)
// ---------------------------------------------------------------------------
__global__ void tobf16_kernel(const float* __restrict__ a, const float* __restrict__ b,
                              unsigned short* __restrict__ oa, unsigned short* __restrict__ ob,
                              int n4)
{
    int i = blockIdx.x * blockDim.x + threadIdx.x;
    const int stride = gridDim.x * blockDim.x;
    for (; i < n4; i += stride) {
        float4 va = ((const float4*)a)[i];
        uint2 pa; pa.x = pack2bf(va.x, va.y); pa.y = pack2bf(va.z, va.w);
        ((uint2*)oa)[i] = pa;
        float4 vb = ((const float4*)b)[i];
        uint2 pb; pb.x = pack2bf(vb.x, vb.y); pb.y = pack2bf(vb.z, vb.w);
        ((uint2*)ob)[i] = pb;
    }
}

// ---------------------------------------------------------------------------
// Merged counting sort over ALL 3 edge sets (R12 lesson: 18 tiny dispatches
// ~= 45us of launch overhead). Joint cnt3[3N] histogram + one exclusive scan
// gives absolute offsets into contiguous rec/ewp arenas (set bases fall out
// of the concatenated scan automatically).
//   rec[p] = { src, dst, ea01(bf16x2), ea23(bf16x2) }  + separate ewp[p].
// ---------------------------------------------------------------------------
__global__ void hist3_kernel(const int* __restrict__ eiB, const int* __restrict__ eiL,
                             const int* __restrict__ eiP,
                             int EB, int EL, int EP, int N, int* __restrict__ cnt3)
{
    const int total = EB + EL + EP;
    for (int e = blockIdx.x * blockDim.x + threadIdx.x; e < total;
         e += gridDim.x * blockDim.x) {
        int base, le; const int* ei; int E;
        if (e < EB)           { base = 0;     le = e;           ei = eiB; E = EB; }
        else if (e < EB + EL) { base = N;     le = e - EB;      ei = eiL; E = EL; }
        else                  { base = 2 * N; le = e - EB - EL; ei = eiP; E = EP; }
        atomicAdd(&cnt3[base + ei[E + le]], 1);
    }
}

__global__ void scan1k_kernel(int* __restrict__ data, int* __restrict__ bsum, int n)
{
    __shared__ int buf[1024];
    const int gid = blockIdx.x * 1024 + threadIdx.x;
    int v = (gid < n) ? data[gid] : 0;
    buf[threadIdx.x] = v;
    __syncthreads();
    for (int off = 1; off < 1024; off <<= 1) {
        int t = (threadIdx.x >= off) ? buf[threadIdx.x - off] : 0;
        __syncthreads();
        buf[threadIdx.x] += t;
        __syncthreads();
    }
    if (gid < n) data[gid] = buf[threadIdx.x] - v;   // exclusive
    if (bsum && threadIdx.x == 1023) bsum[blockIdx.x] = buf[1023];
}

__global__ void scan_add_kernel(int* __restrict__ data, const int* __restrict__ bsum,
                                int* __restrict__ cursor, int n)
{
    const int gid = blockIdx.x * 1024 + threadIdx.x;
    if (gid < n) {
        int v = data[gid] + bsum[blockIdx.x];
        data[gid] = v;
        cursor[gid] = v;
    }
}

__global__ void scatter3_kernel(const int* __restrict__ eiB, const float* __restrict__ ewB,
                                const float4* __restrict__ eaB,
                                const int* __restrict__ eiL, const float* __restrict__ ewL,
                                const float4* __restrict__ eaL,
                                const int* __restrict__ eiP, const float* __restrict__ ewP,
                                const float4* __restrict__ eaP,
                                int EB, int EL, int EP, int N,
                                int* __restrict__ cursor,
                                uint4* __restrict__ rec, float* __restrict__ ewp)
{
    const int total = EB + EL + EP;
    for (int e = blockIdx.x * blockDim.x + threadIdx.x; e < total;
         e += gridDim.x * blockDim.x) {
        int base, le; const int* ei; const float* ew; const float4* ea; int E;
        if (e < EB)           { base = 0;     le = e;           ei = eiB; ew = ewB; ea = eaB; E = EB; }
        else if (e < EB + EL) { base = N;     le = e - EB;      ei = eiL; ew = ewL; ea = eaL; E = EL; }
        else                  { base = 2 * N; le = e - EB - EL; ei = eiP; ew = ewP; ea = eaP; E = EP; }
        int d = ei[E + le];
        int p = atomicAdd(&cursor[base + d], 1);
        float4 a = ea[le];
        uint4 r;
        r.x = (unsigned int)ei[le];
        r.y = (unsigned int)d;
        r.z = pack2bf(a.x, a.y);
        r.w = pack2bf(a.z, a.w);
        rec[p] = r;
        ewp[p] = ew[le];
    }
}

// ---------------------------------------------------------------------------
// Edge kernel (persistent, 512 threads / 8 waves, 64 dst-SORTED edges/tile).
// Wave w owns output cols [32w,32w+32) AND flush rows [8w,8w+8).
// Flush: dst-sorted rows -> fp32 run-reduce over window 8, one fp16x2 atomic
// per distinct dst. UNCHANGED from R12 (proven best: 94us @400k).
// ---------------------------------------------------------------------------
__global__ __launch_bounds__(512, 2)
void edge_mfma_kernel(
    const unsigned short* __restrict__ xsb,   // bf16 x_src (N,128)
    const uint4* __restrict__ rec,            // {src,dst,ea01,ea23} dst-sorted
    const float* __restrict__ ewp,            // dst-sorted edge weights
    const short* __restrict__ pWd, const float* __restrict__ bd,
    const float* __restrict__ Mb, const float* __restrict__ be,
    __half2* __restrict__ agg, int E, int ntiles,
    float rs, float rstep, float rbeta)
{
    __shared__ short sRbf[64 * 128];   // bf16, swizzled [edge][k], 16KB
    __shared__ __half sSS[64 * 256];   // fp16, swizzled [edge][col], 32KB

    const int t = threadIdx.x;
    const int lane = t & 63;
    const int w = t >> 6;          // 0..7
    const int l15 = lane & 15;
    const int l4 = lane >> 4;

    short8_t bfrag[4][2];          // [kk][i], nt = 2w+i
    #pragma unroll
    for (int kk = 0; kk < 4; ++kk)
        #pragma unroll
        for (int i = 0; i < 2; ++i)
            bfrag[kk][i] = *(const short8_t*)&pWd[((kk * 16 + 2 * w + i) * 64 + lane) * 8];
    float bdv[2];
    #pragma unroll
    for (int i = 0; i < 2; ++i) bdv[i] = bd[(2 * w + i) * 16 + l15];
    const float be0 = be[2 * lane], be1 = be[2 * lane + 1];
    float ma0[4], ma1[4];
    #pragma unroll
    for (int a = 0; a < 4; ++a) {
        ma0[a] = Mb[a * 128 + 2 * lane];
        ma1[a] = Mb[a * 128 + 2 * lane + 1];
    }

    const int stride = gridDim.x;
    int tile = blockIdx.x;
    if (tile >= ntiles) return;

    // ---- prologue: record (lane = edge) + gathers for first tile ----
    float ew_c; int src_c, dst_c; unsigned int ea01_c, ea23_c;
    unsigned int gx[8];
    {
        int eL = (tile << 6) + lane;
        int ec = eL < E ? eL : E - 1;
        uint4 r = rec[ec];
        ew_c = ewp[ec];
        src_c = (int)r.x;
        dst_c = (eL < E) ? (int)r.y : -1;
        ea01_c = r.z; ea23_c = r.w;
        #pragma unroll
        for (int rr = 0; rr < 8; ++rr) {
            int srn = __shfl(src_c, 8 * w + rr);
            gx[rr] = *(const unsigned int*)&xsb[(size_t)srn * 128 + lane * 2];
        }
    }

    for (; tile < ntiles; tile += stride) {
        // ---- phase A: rbf -> sRbf, xj -> regs ----
        const float edv = __expf(-ew_c);
        const float dcc = fminf(ew_c, 5.0f);
        const float cutv = 0.5f * (__cosf(dcc * 0.62831853071795864769f) + 1.0f);
        {
            char* base = (char*)sRbf + lane * 256;
            #pragma unroll
            for (int c = 0; c < 2; ++c) {
                short8_t v;
                #pragma unroll
                for (int j = 0; j < 8; ++j) {
                    float mean = rs + (float)(w * 16 + c * 8 + j) * rstep;
                    float diff = edv - mean;
                    v[j] = f2bs(cutv * __expf(-rbeta * diff * diff));
                }
                *(short8_t*)(base + ((w * 32 + c * 16) ^ ((lane & 7) << 4))) = v;
            }
        }
        unsigned int xjr[8];
        #pragma unroll
        for (int r = 0; r < 8; ++r) {
            unsigned int a01 = __shfl(ea01_c, 8 * w + r);
            unsigned int a23 = __shfl(ea23_c, 8 * w + r);
            float ea0 = bs2f(a01 & 0xffffu), ea1 = bs2f(a01 >> 16);
            float ea2 = bs2f(a23 & 0xffffu), ea3 = bs2f(a23 >> 16);
            unsigned int g = gx[r];
            float x0 = bs2f(g & 0xffffu), x1 = bs2f(g >> 16);
            float o0 = x0 + be0 + ea0 * ma0[0] + ea1 * ma0[1] + ea2 * ma0[2] + ea3 * ma0[3];
            float o1 = x1 + be1 + ea0 * ma1[0] + ea1 * ma1[1] + ea2 * ma1[2] + ea3 * ma1[3];
            xjr[r] = pack2bf(o0, o1);
        }

        lds_barrier();   // bar1: sRbf visible (also fences prev-tile sSS reads)

        // ---- phase B ----
        const int ntile = tile + stride;
        const bool has_next = ntile < ntiles;
        float ew_n = 0.f; int src_n = 0, dst_n = -1;
        unsigned int ea01_n = 0, ea23_n = 0;
        if (has_next) {   // issue next-tile record load before any atomics
            int eL = (ntile << 6) + lane;
            int ec = eL < E ? eL : E - 1;
            uint4 r = rec[ec];
            ew_n = ewp[ec];
            src_n = (int)r.x;
            dst_n = (eL < E) ? (int)r.y : -1;
            ea01_n = r.z; ea23_n = r.w;
        }
        __builtin_amdgcn_sched_barrier(0);   // pin prefetch issue before GEMM

        // GEMM: ss(64 x 32cols/wave) = rbf(64x128) @ Wd-slice
        f32x4 acc[4][2];
        #pragma unroll
        for (int m = 0; m < 4; ++m) {
            acc[m][0] = (f32x4){0.f, 0.f, 0.f, 0.f};
            acc[m][1] = (f32x4){0.f, 0.f, 0.f, 0.f};
        }
        #pragma unroll
        for (int kk = 0; kk < 4; ++kk) {
            short8_t af[4];
            #pragma unroll
            for (int m = 0; m < 4; ++m) {
                int row = m * 16 + l15;
                int byte = row * 256 + ((kk * 64 + l4 * 16) ^ ((row & 7) << 4));
                af[m] = *(const short8_t*)((const char*)sRbf + byte);
            }
            #pragma unroll
            for (int m = 0; m < 4; ++m)
                #pragma unroll
                for (int i = 0; i < 2; ++i)
                    acc[m][i] = __builtin_amdgcn_mfma_f32_16x16x32_bf16(
                        af[m], bfrag[kk][i], acc[m][i], 0, 0, 0);
        }

        // ss = acc + bd -> sSS fp16 (swizzled [edge][col])
        #pragma unroll
        for (int m = 0; m < 4; ++m)
            #pragma unroll
            for (int i = 0; i < 2; ++i) {
                int col = (2 * w + i) * 16 + l15;
                #pragma unroll
                for (int r = 0; r < 4; ++r) {
                    int row = m * 16 + l4 * 4 + r;
                    int byte = row * 512 + ((col * 2) ^ ((row & 7) << 4));
                    *(__half*)((char*)sSS + byte) = __float2half(acc[m][i][r] + bdv[i]);
                }
            }

        // issue next-tile gathers (acc dead; still before atomics)
        if (has_next) {
            #pragma unroll
            for (int r = 0; r < 8; ++r) {
                int srn = __shfl(src_n, 8 * w + r);
                gx[r] = *(const unsigned int*)&xsb[(size_t)srn * 128 + lane * 2];
            }
        }
        const int dst_f = dst_c;
        ew_c = ew_n; src_c = src_n; dst_c = dst_n; ea01_c = ea01_n; ea23_c = ea23_n;

        lds_barrier();   // bar2: sSS visible; sRbf GEMM reads done

        // ---- phase C: segmented run-reduce flush (rows 8w..8w+8, dst-sorted) ----
        {
            float a0 = 0.f, a1 = 0.f;
            int rdst = __shfl(dst_f, 8 * w);
            #pragma unroll
            for (int r = 0; r < 8; ++r) {
                int e = 8 * w + r;
                unsigned int sc = *(const unsigned int*)
                    ((const char*)sSS + e * 512 + ((lane * 4) ^ ((e & 7) << 4)));
                unsigned int sh = *(const unsigned int*)
                    ((const char*)sSS + e * 512 + ((256 + lane * 4) ^ ((e & 7) << 4)));
                float2 scf = __half22float2(*(const __half2*)&sc);
                float2 shf = __half22float2(*(const __half2*)&sh);
                unsigned int g = xjr[r];
                float x0 = bs2f(g & 0xffffu), x1 = bs2f(g >> 16);
                float m0 = fmaxf(fmaf(x0, scf.x, shf.x), 0.0f);
                float m1 = fmaxf(fmaf(x1, scf.y, shf.y), 0.0f);
                int d = __shfl(dst_f, e);
                if (d != rdst) {
                    if (rdst >= 0) {
                        __half2 hv = __floats2half2_rn(a0, a1);
                        unsigned int hb;
                        __builtin_memcpy(&hb, &hv, 4);
                        if (hb)
                            unsafeAtomicAdd(agg + (size_t)rdst * 64 + lane, hv);
                    }
                    a0 = 0.f; a1 = 0.f; rdst = d;
                }
                a0 += m0; a1 += m1;
            }
            if (rdst >= 0) {
                __half2 hv = __floats2half2_rn(a0, a1);
                unsigned int hb;
                __builtin_memcpy(&hb, &hv, 4);
                if (hb)
                    unsafeAtomicAdd(agg + (size_t)rdst * 64 + lane, hv);
            }
        }
    }
}

// ---------------------------------------------------------------------------
// Node kernel (persistent): out = relu((agg+x)@W1+b1)@W2+b2 (+prev, relu opt)
// Persistent weight frags; zeroes agg in place after reading it.
// UNCHANGED from R12.
// ---------------------------------------------------------------------------
__global__ __launch_bounds__(256)
void node_mfma_kernel(
    __half2* __restrict__ agg,
    const float* __restrict__ xdf, const unsigned short* __restrict__ xdb,
    const short* __restrict__ pW1, const float* __restrict__ b1,
    const short* __restrict__ pW2, const float* __restrict__ b2,
    float* __restrict__ outf, unsigned short* __restrict__ outb,
    int N, int ntiles, int accumulate, int relu_out)
{
    __shared__ short sA[64 * 128];
    __shared__ short sH[64 * 128];

    const int t = threadIdx.x;
    const int lane = t & 63;
    const int w = t >> 6;
    const int l15 = lane & 15;
    const int l4 = lane >> 4;

    short8_t w1f[4][2], w2f[4][2];
    #pragma unroll
    for (int kk = 0; kk < 4; ++kk)
        #pragma unroll
        for (int p = 0; p < 2; ++p) {
            int nt = 2 * w + p;
            w1f[kk][p] = *(const short8_t*)&pW1[((kk * 8 + nt) * 64 + lane) * 8];
            w2f[kk][p] = *(const short8_t*)&pW2[((kk * 8 + nt) * 64 + lane) * 8];
        }
    float b1v[2], b2v[2];
    #pragma unroll
    for (int p = 0; p < 2; ++p) {
        int col = (2 * w + p) * 16 + l15;
        b1v[p] = b1[col];
        b2v[p] = b2[col];
    }

    const float4 zero4 = {0.f, 0.f, 0.f, 0.f};

    for (int tile = blockIdx.x; tile < ntiles; tile += gridDim.x) {
        const int n0 = tile << 6;
        // --- stage A = bf16(fp16 agg + x_dst); zero agg after read ---
        #pragma unroll
        for (int i = 0; i < 4; ++i) {
            int idx = i * 256 + t;
            int row = idx >> 4, c8 = idx & 15;
            int gr = n0 + row; if (gr >= N) gr = N - 1;
            union { float4 f; __half2 h[4]; } ar;
            ar.f = ((const float4*)agg)[(size_t)gr * 16 + c8];
            ((float4*)agg)[(size_t)gr * 16 + c8] = zero4;   // reset for next conv
            float xv[8];
            if (xdf) {
                float4 x0 = ((const float4*)xdf)[(size_t)gr * 32 + c8 * 2];
                float4 x1 = ((const float4*)xdf)[(size_t)gr * 32 + c8 * 2 + 1];
                xv[0] = x0.x; xv[1] = x0.y; xv[2] = x0.z; xv[3] = x0.w;
                xv[4] = x1.x; xv[5] = x1.y; xv[6] = x1.z; xv[7] = x1.w;
            } else {
                uint4 xr = ((const uint4*)xdb)[(size_t)gr * 16 + c8];
                xv[0] = bs2f(xr.x & 0xffffu); xv[1] = bs2f(xr.x >> 16);
                xv[2] = bs2f(xr.y & 0xffffu); xv[3] = bs2f(xr.y >> 16);
                xv[4] = bs2f(xr.z & 0xffffu); xv[5] = bs2f(xr.z >> 16);
                xv[6] = bs2f(xr.w & 0xffffu); xv[7] = bs2f(xr.w >> 16);
            }
            short8_t v;
            #pragma unroll
            for (int j = 0; j < 4; ++j) {
                float2 a2 = __half22float2(ar.h[j]);
                v[2 * j]     = f2bs(a2.x + xv[2 * j]);
                v[2 * j + 1] = f2bs(a2.y + xv[2 * j + 1]);
            }
            int byte = row * 256 + ((c8 * 16) ^ ((row & 7) << 4));
            *(short8_t*)((char*)sA + byte) = v;
        }
        lds_barrier();

        f32x4 acc[4][2];
        #pragma unroll
        for (int m = 0; m < 4; ++m) {
            acc[m][0] = (f32x4){0.f, 0.f, 0.f, 0.f};
            acc[m][1] = (f32x4){0.f, 0.f, 0.f, 0.f};
        }
        #pragma unroll
        for (int kk = 0; kk < 4; ++kk) {
            short8_t af[4];
            #pragma unroll
            for (int m = 0; m < 4; ++m) {
                int row = m * 16 + l15;
                int byte = row * 256 + ((kk * 64 + l4 * 16) ^ ((row & 7) << 4));
                af[m] = *(const short8_t*)((const char*)sA + byte);
            }
            #pragma unroll
            for (int m = 0; m < 4; ++m)
                #pragma unroll
                for (int p = 0; p < 2; ++p)
                    acc[m][p] = __builtin_amdgcn_mfma_f32_16x16x32_bf16(
                        af[m], w1f[kk][p], acc[m][p], 0, 0, 0);
        }
        #pragma unroll
        for (int m = 0; m < 4; ++m)
            #pragma unroll
            for (int p = 0; p < 2; ++p) {
                int col = (2 * w + p) * 16 + l15;
                #pragma unroll
                for (int r = 0; r < 4; ++r) {
                    int row = m * 16 + l4 * 4 + r;
                    short hs = f2bs(fmaxf(acc[m][p][r] + b1v[p], 0.f));
                    int byte = row * 256 + ((col * 2) ^ ((row & 7) << 4));
                    *(short*)((char*)sH + byte) = hs;
                }
            }
        lds_barrier();

        f32x4 acc2[4][2];
        #pragma unroll
        for (int m = 0; m < 4; ++m) {
            acc2[m][0] = (f32x4){0.f, 0.f, 0.f, 0.f};
            acc2[m][1] = (f32x4){0.f, 0.f, 0.f, 0.f};
        }
        #pragma unroll
        for (int kk = 0; kk < 4; ++kk) {
            short8_t af[4];
            #pragma unroll
            for (int m = 0; m < 4; ++m) {
                int row = m * 16 + l15;
                int byte = row * 256 + ((kk * 64 + l4 * 16) ^ ((row & 7) << 4));
                af[m] = *(const short8_t*)((const char*)sH + byte);
            }
            #pragma unroll
            for (int m = 0; m < 4; ++m)
                #pragma unroll
                for (int p = 0; p < 2; ++p)
                    acc2[m][p] = __builtin_amdgcn_mfma_f32_16x16x32_bf16(
                        af[m], w2f[kk][p], acc2[m][p], 0, 0, 0);
        }
        #pragma unroll
        for (int m = 0; m < 4; ++m)
            #pragma unroll
            for (int p = 0; p < 2; ++p) {
                int col = (2 * w + p) * 16 + l15;
                #pragma unroll
                for (int r = 0; r < 4; ++r) {
                    int row = n0 + m * 16 + l4 * 4 + r;
                    if (row < N) {
                        float v = acc2[m][p][r] + b2v[p];
                        if (outf) {
                            float* op = &outf[(size_t)row * 128 + col];
                            if (accumulate) v += *op;
                            if (relu_out) v = fmaxf(v, 0.f);
                            *op = v;
                        } else {
                            unsigned short* op = &outb[(size_t)row * 128 + col];
                            if (accumulate) v += bs2f((unsigned int)*op);
                            if (relu_out) v = fmaxf(v, 0.f);
                            *op = (unsigned short)f2bs(v);
                        }
                    }
                }
            }
    }
}

// ---------------------------------------------------------------------------
extern "C" void kernel_launch(void* const* d_in, const int* in_sizes, int n_in,
                              void* d_out, int out_size, void* d_ws, size_t ws_size,
                              hipStream_t stream)
{
    const float* x_lig   = (const float*)d_in[0];
    const float* x_pock  = (const float*)d_in[1];
    const int*   ei_bond = (const int*)d_in[2];
    const float* ew_bond = (const float*)d_in[3];
    const float* ea_bond = (const float*)d_in[4];
    const int*   ei_lp   = (const int*)d_in[5];
    const float* ew_lp   = (const float*)d_in[6];
    const float* ea_lp   = (const float*)d_in[7];
    const int*   ei_pl   = (const int*)d_in[8];
    const float* ew_pl   = (const float*)d_in[9];
    const float* ea_pl   = (const float*)d_in[10];
    const float* W0 = (const float*)d_in[11];
    const float* Wd = (const float*)d_in[12];
    const float* bd = (const float*)d_in[13];
    const float* We = (const float*)d_in[14];
    const float* be = (const float*)d_in[15];
    const float* W1 = (const float*)d_in[16];
    const float* b1 = (const float*)d_in[17];
    const float* W2 = (const float*)d_in[18];
    const float* b2 = (const float*)d_in[19];

    const int H = 128;
    const int N = in_sizes[0] / H;
    const int E_bond = in_sizes[3];
    const int E_lp   = in_sizes[6];
    const int E_pl   = in_sizes[9];
    const int E_all  = E_bond + E_lp + E_pl;

    // ---- workspace layout (256B-aligned bump allocator), ~126MB ----
    char* wp = (char*)d_ws;
    auto alloc = [&](size_t bytes) -> char* {
        char* r = wp;
        wp += (bytes + 255) & ~(size_t)255;
        return r;
    };
    unsigned short* A   = (unsigned short*)alloc((size_t)N * H * 2);
    unsigned short* Bb  = (unsigned short*)alloc((size_t)N * H * 2);
    unsigned short* C   = (unsigned short*)alloc((size_t)N * H * 2);
    __half*  agg  = (__half*)alloc((size_t)N * H * 2);   // | start of zeroed span
    int*     cnt3 = (int*)alloc((size_t)3 * N * 4);      // | (agg..cnt3 one memset)
    char*    zero_end = wp;
    uint4*   recAll = (uint4*)alloc((size_t)E_all * 16);
    float*   ewpAll = (float*)alloc((size_t)E_all * 4);
    short*   pWd  = (short*)alloc(6 * 32768 * 2);
    short*   pW1s = (short*)alloc(6 * 16384 * 2);
    short*   pW2s = (short*)alloc(6 * 16384 * 2);
    float*   Mb   = (float*)alloc(6 * 512 * 4);
    int*     cursor = (int*)alloc((size_t)3 * N * 4);
    int*     bsum   = (int*)alloc(1024 * 4);

    const uint4* recB = recAll;
    const uint4* recL = recAll + E_bond;
    const uint4* recP = recAll + E_bond + E_lp;
    const float* ewpB = ewpAll;
    const float* ewpL = ewpAll + E_bond;
    const float* ewpP = ewpAll + E_bond + E_lp;

    float* outL = (float*)d_out;
    float* outP = outL + (size_t)N * H;

    const int capE = 256;        // 1 resident 512-thr block/CU (R10/R12 proven)
    const int capN = 4 * 256;

    // One memset covers agg (25.6MB) + cnt3 (1.2MB) — adjacent in ws.
    hipMemsetAsync(agg, 0, (size_t)(zero_end - (char*)agg), stream);
    tobf16_kernel<<<512, 256, 0, stream>>>(x_lig, x_pock, A, Bb, N * H / 4);
    pack_kernel<<<256, 256, 0, stream>>>(Wd, W1, W2, W0, We, pWd, pW1s, pW2s, Mb);

    // ---- merged dst-sort of all 3 edge sets (4 dispatches total) ----
    const int n3 = 3 * N;
    const int nb3 = (n3 + 1023) / 1024;
    hist3_kernel<<<1024, 256, 0, stream>>>(ei_bond, ei_lp, ei_pl,
                                           E_bond, E_lp, E_pl, N, cnt3);
    scan1k_kernel<<<nb3, 1024, 0, stream>>>(cnt3, bsum, n3);
    scan1k_kernel<<<1, 1024, 0, stream>>>(bsum, nullptr, nb3);
    scan_add_kernel<<<nb3, 1024, 0, stream>>>(cnt3, bsum, cursor, n3);
    scatter3_kernel<<<1024, 256, 0, stream>>>(
        ei_bond, ew_bond, (const float4*)ea_bond,
        ei_lp,   ew_lp,   (const float4*)ea_lp,
        ei_pl,   ew_pl,   (const float4*)ea_pl,
        E_bond, E_lp, E_pl, N, cursor, recAll, ewpAll);

    const double start_d = exp(-5.0);
    const float rs    = (float)start_d;
    const float rstep = (float)((1.0 - start_d) / 127.0);
    const float rbeta = (float)std::pow(2.0 / 128.0 * (1.0 - start_d), -2.0);

    auto conv = [&](const unsigned short* src,
                    const float* xdf, const unsigned short* xdb,
                    const uint4* rec, const float* ewp, int E,
                    int l, int tt, float* outf, unsigned short* outb,
                    int accum, int relu) {
        const int lt = l * 3 + tt;
        const int ntE = (E + 63) / 64;
        const int gE = ntE < capE ? ntE : capE;
        edge_mfma_kernel<<<gE, 512, 0, stream>>>(
            src, rec, ewp,
            pWd + (size_t)lt * 32768, bd + (size_t)lt * 256,
            Mb + (size_t)lt * 512, be + (size_t)lt * 128,
            (__half2*)agg, E, ntE, rs, rstep, rbeta);
        const int ntN = (N + 63) / 64;
        const int gN = ntN < capN ? ntN : capN;
        node_mfma_kernel<<<gN, 256, 0, stream>>>(
            (__half2*)agg, xdf, xdb,
            pW1s + (size_t)lt * 16384, b1 + (size_t)lt * 128,
            pW2s + (size_t)lt * 16384, b2 + (size_t)lt * 128,
            outf, outb, N, ntN, accum, relu);
    };

    // layer 0 (order matters: A is overwritten by bond0's node after lp0+bond0 edges read it)
    conv(A,  x_pock, nullptr, recL, ewpL, E_lp,   0, 1, nullptr, C, 0, 1);
    conv(A,  x_lig,  nullptr, recB, ewpB, E_bond, 0, 0, nullptr, A, 0, 0);
    conv(Bb, x_lig,  nullptr, recP, ewpP, E_pl,   0, 2, nullptr, A, 1, 1);
    // layer 1: lig_bf = A, pock_bf = C
    conv(A, nullptr, A, recB, ewpB, E_bond, 1, 0, outL, nullptr, 0, 0);
    conv(C, nullptr, A, recP, ewpP, E_pl,   1, 2, outL, nullptr, 1, 0);
    conv(A, nullptr, C, recL, ewpL, E_lp,   1, 1, outP, nullptr, 0, 0);
}